// Round 13
// baseline (234.835 us; speedup 1.0000x reference)
//
#include <hip/hip_runtime.h>

typedef __bf16 bf16x8 __attribute__((ext_vector_type(8)));
typedef __bf16 bf16x4 __attribute__((ext_vector_type(4)));
typedef __bf16 bf16x2 __attribute__((ext_vector_type(2)));
typedef float  f32x4  __attribute__((ext_vector_type(4)));

// CK-pattern async global->LDS (16B per lane, wave-uniform LDS base).
__device__ __forceinline__ void gload_lds16(const void* g, void* l) {
    auto gp = reinterpret_cast<const __attribute__((address_space(1))) unsigned int*>(
        reinterpret_cast<uintptr_t>(g));
    auto lp = reinterpret_cast<__attribute__((address_space(3))) unsigned int*>(
        reinterpret_cast<uintptr_t>(l));
    __builtin_amdgcn_global_load_lds(gp, lp, 16, 0, 0);
}

// Raw barriers with counted waits (T4/m201 discipline).  __syncthreads emits
// vmcnt(0) before s_barrier (drains prefetches); these do not.
__device__ __forceinline__ void barrier_lgkm() {
    __builtin_amdgcn_sched_barrier(0);
    asm volatile("s_waitcnt lgkmcnt(0)" ::: "memory");
    __builtin_amdgcn_s_barrier();
    __builtin_amdgcn_sched_barrier(0);
}
__device__ __forceinline__ void barrier_vm2_lgkm() {
    __builtin_amdgcn_sched_barrier(0);
    asm volatile("s_waitcnt vmcnt(2) lgkmcnt(0)" ::: "memory");
    __builtin_amdgcn_s_barrier();
    __builtin_amdgcn_sched_barrier(0);
}
__device__ __forceinline__ void barrier_vm0_lgkm() {
    __builtin_amdgcn_sched_barrier(0);
    asm volatile("s_waitcnt vmcnt(0) lgkmcnt(0)" ::: "memory");
    __builtin_amdgcn_s_barrier();
    __builtin_amdgcn_sched_barrier(0);
}

// XCD-aware swizzle for 512-block GEMM grids (8 n-blocks x 64 m-rows).
__device__ __forceinline__ void xcd_remap(int lin, int& bx, int& by) {
    const int wgid = (lin & 7) * 64 + (lin >> 3);
    bx = wgid & 7;
    by = wgid >> 3;
}

// ---------------------------------------------------------------------------
// Merged prep (1 launch): Wq/Wo transposes + addresses->bf16.  (unchanged)
// ---------------------------------------------------------------------------
__global__ __launch_bounds__(256) void prep_all(
    const float* __restrict__ Wq, const float* __restrict__ Wo,
    const float* __restrict__ adr,
    __bf16* __restrict__ WqT, __bf16* __restrict__ WoT,
    __bf16* __restrict__ adrb)
{
    __shared__ float tile[32][33];
    const int bid = blockIdx.x, tid = threadIdx.x;

    if (bid < 1024) {
        const float* src; __bf16* dst; int R, C, r0, c0;
        if (bid < 512) {             // Wq [1024][512] -> WqT [512][1024]
            src = Wq; dst = WqT; R = 1024; C = 512;
            c0 = (bid & 15) * 32; r0 = (bid >> 4) * 32;
        } else {                     // Wo [512][1024] -> WoT [1024][512]
            const int b = bid - 512;
            src = Wo; dst = WoT; R = 512; C = 1024;
            c0 = (b & 31) * 32; r0 = (b >> 5) * 32;
        }
        const int tx = tid & 31, ty = tid >> 5;
        #pragma unroll
        for (int i = ty; i < 32; i += 8)
            tile[i][tx] = src[(size_t)(r0 + i) * C + c0 + tx];
        __syncthreads();
        #pragma unroll
        for (int i = ty; i < 32; i += 8)
            dst[(size_t)(c0 + i) * R + r0 + tx] = (__bf16)tile[tx][i];
    } else {                         // addresses [128][64] f32 -> bf16
        const int i = (bid - 1024) * 256 + tid;
        f32x4 a = ((const f32x4*)adr)[2 * i];
        f32x4 b = ((const f32x4*)adr)[2 * i + 1];
        bf16x8 o;
        #pragma unroll
        for (int j = 0; j < 4; ++j) { o[j] = (__bf16)a[j]; o[4 + j] = (__bf16)b[j]; }
        ((bf16x8*)adrb)[i] = o;
    }
}

// ---------------------------------------------------------------------------
// Q-proj GEMM, 512 threads (8 waves, 4m x 2n; wave tile 32x32), 2-step-deep
// register pipeline on BOTH operands + raw lgkm-only barrier: at step t,
// load tile t+2 to regs, compute tile t from LDS, ds_write tile t+1.
// Reg-load waits land at the ds_writes (1 full step of covered latency);
// no vmcnt drain at barriers.
// ---------------------------------------------------------------------------
__global__ __launch_bounds__(512) void gemm_qproj(
    const float* __restrict__ A, const __bf16* __restrict__ BT,
    const float* __restrict__ bias, __bf16* __restrict__ Out,
    int M, int N, int K)
{
    __shared__ __bf16 As[2][128][40];
    __shared__ __bf16 Bs[2][64][32];

    const int tid = threadIdx.x, lane = tid & 63, w = tid >> 6;
    const int wm = w >> 1, wn = w & 1;          // 4 x 2 wave grid
    int bx, by;
    xcd_remap(blockIdx.x + 8 * blockIdx.y, bx, by);
    const int m0 = by * 128, n0 = bx * 64;
    const int r = lane & 15, g = lane >> 4;

    const int arow = tid >> 2, ac8 = (tid & 3) * 8;     // A: 8 f32/thread
    const float* gA = A + (size_t)(m0 + arow) * K + ac8;
    const bool bstage = (w < 4);                        // B: waves 0-3 only
    const int brow = 16 * (w & 3) + (lane >> 2), bc8 = (lane & 3) * 8;
    const __bf16* gB = BT + (size_t)(n0 + brow) * K + bc8;

    f32x4 acc[2][2];
    const f32x4 zero = {0.f, 0.f, 0.f, 0.f};
    #pragma unroll
    for (int mi = 0; mi < 2; ++mi)
        #pragma unroll
        for (int ni = 0; ni < 2; ++ni) acc[mi][ni] = zero;

    const int NT = K / 32;                              // 32

    // pipeline register sets: set[ph] holds tile loaded with phase ph
    f32x4 pa0[2], pa1[2];
    bf16x8 pb[2];

    // ---- prologue: load tile0 -> set[0], tile1 -> set[1]; write tile0 ----
    pa0[0] = *(const f32x4*)(gA);      pa1[0] = *(const f32x4*)(gA + 4);
    pa0[1] = *(const f32x4*)(gA + 32); pa1[1] = *(const f32x4*)(gA + 36);
    if (bstage) { pb[0] = *(const bf16x8*)(gB); pb[1] = *(const bf16x8*)(gB + 32); }
    {
        bf16x8 bl;
        #pragma unroll
        for (int j = 0; j < 4; ++j) { bl[j] = (__bf16)pa0[0][j]; bl[4 + j] = (__bf16)pa1[0][j]; }
        *(bf16x8*)&As[0][arow][ac8] = bl;
        if (bstage) *(bf16x8*)&Bs[0][brow][bc8] = pb[0];
    }
    barrier_lgkm();

    #pragma unroll 2
    for (int t = 0; t < NT; ++t) {
        const int ph = t & 1;
        // ---- load tile t+2 into set[ph] (tile t in set[ph] is dead) ----
        if (t + 2 < NT) {
            pa0[ph] = *(const f32x4*)(gA + (t + 2) * 32);
            pa1[ph] = *(const f32x4*)(gA + (t + 2) * 32 + 4);
            if (bstage) pb[ph] = *(const bf16x8*)(gB + (t + 2) * 32);
        }
        // ---- compute tile t from LDS[ph] ----
        bf16x8 af[2], bfr[2];
        #pragma unroll
        for (int mi = 0; mi < 2; ++mi)
            af[mi] = *(const bf16x8*)&As[ph][wm * 32 + mi * 16 + r][g * 8];
        #pragma unroll
        for (int ni = 0; ni < 2; ++ni)
            bfr[ni] = *(const bf16x8*)&Bs[ph][wn * 32 + ni * 16 + r][g * 8];
        #pragma unroll
        for (int mi = 0; mi < 2; ++mi)
            #pragma unroll
            for (int ni = 0; ni < 2; ++ni)
                acc[mi][ni] = __builtin_amdgcn_mfma_f32_16x16x32_bf16(
                    af[mi], bfr[ni], acc[mi][ni], 0, 0, 0);
        // ---- write tile t+1 (set[ph^1], loaded at t-1) to LDS[ph^1] ----
        if (t + 1 < NT) {
            bf16x8 bl;
            #pragma unroll
            for (int j = 0; j < 4; ++j) {
                bl[j]     = (__bf16)pa0[ph ^ 1][j];
                bl[4 + j] = (__bf16)pa1[ph ^ 1][j];
            }
            *(bf16x8*)&As[ph ^ 1][arow][ac8] = bl;
            if (bstage) *(bf16x8*)&Bs[ph ^ 1][brow][bc8] = pb[ph ^ 1];
        }
        barrier_lgkm();
    }

    const int orow = m0 + wm * 32 + g * 4;
    const int ocol = n0 + wn * 32 + r;
    #pragma unroll
    for (int ni = 0; ni < 2; ++ni) {
        const float bb = bias[ocol + ni * 16];
        #pragma unroll
        for (int mi = 0; mi < 2; ++mi) {
            #pragma unroll
            for (int q = 0; q < 4; ++q) {
                float v = fmaxf(acc[mi][ni][q] + bb, 0.f);
                Out[(size_t)(orow + mi * 16 + q) * N + ocol + ni * 16] = (__bf16)v;
            }
        }
    }
}

// ---------------------------------------------------------------------------
// Out-proj GEMM, 512 threads (8 waves, 4m x 2n; wave tile 32x64), 3-buffer
// gload_lds rotation + counted vmcnt(2) raw barriers: tile t+2's DMAs stay
// in flight across the barrier; only tile t+1's must land.
// ---------------------------------------------------------------------------
__global__ __launch_bounds__(512) void gemm_oproj(
    const __bf16* __restrict__ A, const __bf16* __restrict__ BT,
    const float* __restrict__ bias, float* __restrict__ Out,
    int M, int N, int K)
{
    __shared__ __bf16 As[3][128][32];
    __shared__ __bf16 Bs[3][128][32];

    const int tid = threadIdx.x, lane = tid & 63, w = tid >> 6;
    const int wm = w >> 1, wn = w & 1;          // 4 x 2 wave grid
    int bx, by;
    xcd_remap(blockIdx.x + 8 * blockIdx.y, bx, by);
    const int m0 = by * 128, n0 = bx * 128;
    const int r = lane & 15, g = lane >> 4;

    const int srow = lane >> 2;
    const int scol = (lane & 3) * 8;
    const __bf16* gA = A  + (size_t)(m0 + 16 * w + srow) * K + scol;
    const __bf16* gB = BT + (size_t)(n0 + 16 * w + srow) * K + scol;

    f32x4 acc[2][4];
    const f32x4 zero = {0.f, 0.f, 0.f, 0.f};
    #pragma unroll
    for (int mi = 0; mi < 2; ++mi)
        #pragma unroll
        for (int ni = 0; ni < 4; ++ni) acc[mi][ni] = zero;

    const int NT = K / 32;                              // 16

    // ---- prologue: issue tile0 -> buf0, tile1 -> buf1 ----
    gload_lds16(gA,      &As[0][16 * w][0]);
    gload_lds16(gB,      &Bs[0][16 * w][0]);
    gload_lds16(gA + 32, &As[1][16 * w][0]);
    gload_lds16(gB + 32, &Bs[1][16 * w][0]);
    // tile0 must be complete (2 newest = tile1's stay in flight)
    __builtin_amdgcn_sched_barrier(0);
    asm volatile("s_waitcnt vmcnt(2)" ::: "memory");
    __builtin_amdgcn_s_barrier();
    __builtin_amdgcn_sched_barrier(0);

    int buf = 0;
    for (int t = 0; t < NT; ++t) {
        // ---- issue tile t+2 into buf[(t+2)%3] ----
        if (t + 2 < NT) {
            const int nb = (buf + 2 >= 3) ? buf - 1 : buf + 2;
            gload_lds16(gA + (t + 2) * 32, &As[nb][16 * w][0]);
            gload_lds16(gB + (t + 2) * 32, &Bs[nb][16 * w][0]);
        }
        // ---- compute tile t from buf ----
        bf16x8 af[2], bfr[4];
        #pragma unroll
        for (int mi = 0; mi < 2; ++mi)
            af[mi] = *(const bf16x8*)&As[buf][wm * 32 + mi * 16 + r][g * 8];
        #pragma unroll
        for (int ni = 0; ni < 4; ++ni)
            bfr[ni] = *(const bf16x8*)&Bs[buf][wn * 64 + ni * 16 + r][g * 8];
        #pragma unroll
        for (int mi = 0; mi < 2; ++mi)
            #pragma unroll
            for (int ni = 0; ni < 4; ++ni)
                acc[mi][ni] = __builtin_amdgcn_mfma_f32_16x16x32_bf16(
                    af[mi], bfr[ni], acc[mi][ni], 0, 0, 0);
        // ---- barrier: tile t+1 ready; t+2 (if any) stays in flight ----
        if (t + 1 < NT) {
            if (t + 2 < NT) barrier_vm2_lgkm();
            else            barrier_vm0_lgkm();
        }
        buf = (buf + 1 >= 3) ? 0 : buf + 1;
    }

    const int orow = m0 + wm * 32 + g * 4;
    const int ocol = n0 + wn * 64 + r;
    #pragma unroll
    for (int ni = 0; ni < 4; ++ni) {
        const float bb = bias[ocol + ni * 16];
        #pragma unroll
        for (int mi = 0; mi < 2; ++mi) {
            #pragma unroll
            for (int q = 0; q < 4; ++q) {
                Out[(size_t)(orow + mi * 16 + q) * N + ocol + ni * 16]
                    = acc[mi][ni][q] + bb;
            }
        }
    }
}

// ---------------------------------------------------------------------------
// Fused memory attention (MFMA) — at HBM floor (43.7 µs, r8).  Do not touch.
// ---------------------------------------------------------------------------
__device__ __forceinline__ int kbyte(int m, int e) {
    return m * 128 + ((((e >> 3) ^ (m & 7))) << 4) + (e & 7) * 2;
}

__global__ void memory_attn_mfma(
    const __bf16* __restrict__ Q,      // [N][512] bf16 (relu'd q proj)
    const float*  __restrict__ mem,    // [N][128][64] f32
    const __bf16* __restrict__ adrb,   // [128][64] bf16
    __bf16* __restrict__ attn)         // [N][512] bf16
{
    __shared__ __align__(16) unsigned char kbuf[4][4096];
    __shared__ __align__(16) unsigned char tbuf[4][5120];
    __shared__ float denl[4][8];

    const int tid = threadIdx.x, lane = tid & 63, w = tid >> 6;
    const int n = blockIdx.x * 4 + w;
    const int v = lane & 15, g = lane >> 4;

    unsigned char* kb = kbuf[w];
    unsigned char* tb = tbuf[w];

    const __bf16* qp = Q + (size_t)n * 512 + v * 64 + 8 * g;
    const bf16x8 qf0 = *(const bf16x8*)(qp);
    const bf16x8 qf1 = *(const bf16x8*)(qp + 32);

    f32x4 acc[4];
    const f32x4 zero = {0.f, 0.f, 0.f, 0.f};
    #pragma unroll
    for (int nb = 0; nb < 4; ++nb) acc[nb] = zero;
    float psum = 0.f;

    for (int c = 0; c < 4; ++c) {
        const int mb = c * 32;
        #pragma unroll
        for (int i = 0; i < 4; ++i) {
            const int mo = 8 * i + 2 * g;
            const int e  = 4 * v;
            const float* pm = mem + (((size_t)n * 128 + mb + mo) * 64 + e);
            const f32x4 m0 = *(const f32x4*)pm;
            const f32x4 m1 = *(const f32x4*)(pm + 64);
            const bf16x4 a0 = *(const bf16x4*)(adrb + (size_t)(mb + mo) * 64 + e);
            const bf16x4 a1 = *(const bf16x4*)(adrb + (size_t)(mb + mo + 1) * 64 + e);
            bf16x4 k0, k1;
            #pragma unroll
            for (int j = 0; j < 4; ++j) {
                k0[j] = (__bf16)fmaxf(m0[j] + (float)a0[j], 0.f);
                k1[j] = (__bf16)fmaxf(m1[j] + (float)a1[j], 0.f);
            }
            *(bf16x4*)(kb + kbyte(mo,     e)) = k0;
            *(bf16x4*)(kb + kbyte(mo + 1, e)) = k1;
            const int kap = 8 * ((mo >> 2) & 3) + 4 * (mo >> 4) + (mo & 3);
            #pragma unroll
            for (int j2 = 0; j2 < 4; ++j2) {
                bf16x2 p = { (__bf16)m0[j2], (__bf16)m1[j2] };
                *(bf16x2*)(tb + (size_t)(e + j2) * 80 + kap * 2) = p;
            }
        }

        f32x4 sA0 = zero, sA1 = zero;
        {
            const bf16x8 a00 = *(const bf16x8*)(kb + kbyte(v,      8 * g));
            const bf16x8 a01 = *(const bf16x8*)(kb + kbyte(v,      32 + 8 * g));
            const bf16x8 a10 = *(const bf16x8*)(kb + kbyte(v + 16, 8 * g));
            const bf16x8 a11 = *(const bf16x8*)(kb + kbyte(v + 16, 32 + 8 * g));
            sA0 = __builtin_amdgcn_mfma_f32_16x16x32_bf16(a00, qf0, sA0, 0, 0, 0);
            sA0 = __builtin_amdgcn_mfma_f32_16x16x32_bf16(a01, qf1, sA0, 0, 0, 0);
            sA1 = __builtin_amdgcn_mfma_f32_16x16x32_bf16(a10, qf0, sA1, 0, 0, 0);
            sA1 = __builtin_amdgcn_mfma_f32_16x16x32_bf16(a11, qf1, sA1, 0, 0, 0);
        }
        psum += sA0[0] + sA0[1] + sA0[2] + sA0[3]
              + sA1[0] + sA1[1] + sA1[2] + sA1[3];

        bf16x8 pa;
        #pragma unroll
        for (int q = 0; q < 4; ++q) {
            pa[q]     = (__bf16)sA0[q];
            pa[4 + q] = (__bf16)sA1[q];
        }

        #pragma unroll
        for (int nb = 0; nb < 4; ++nb) {
            const bf16x8 bf = *(const bf16x8*)(tb + (size_t)(16 * nb + v) * 80 + 16 * g);
            acc[nb] = __builtin_amdgcn_mfma_f32_16x16x32_bf16(pa, bf, acc[nb], 0, 0, 0);
        }
    }

    psum += __shfl_xor(psum, 16);
    psum += __shfl_xor(psum, 32);
    if (lane < 8) denl[w][lane] = psum;

    if (g < 2) {
        const f32x4 d4 = *(const f32x4*)&denl[w][4 * g];
        float inv[4];
        #pragma unroll
        for (int q = 0; q < 4; ++q) inv[q] = 1.f / (d4[q] + 1e-5f);
        #pragma unroll
        for (int nb = 0; nb < 4; ++nb) {
            #pragma unroll
            for (int q = 0; q < 4; ++q) {
                attn[(size_t)n * 512 + (4 * g + q) * 64 + 16 * nb + v] =
                    (__bf16)(acc[nb][q] * inv[q]);
            }
        }
    }
}

// ---------------------------------------------------------------------------
extern "C" void kernel_launch(void* const* d_in, const int* in_sizes, int n_in,
                              void* d_out, int out_size, void* d_ws, size_t ws_size,
                              hipStream_t stream)
{
    const float* query     = (const float*)d_in[0];
    const float* addresses = (const float*)d_in[1];
    const float* memories  = (const float*)d_in[2];
    const float* Wq        = (const float*)d_in[3];
    const float* bq        = (const float*)d_in[4];
    const float* Wo        = (const float*)d_in[5];
    const float* bo        = (const float*)d_in[6];
    float* out = (float*)d_out;

    char* ws = (char*)d_ws;
    __bf16* WqT  = (__bf16*)(ws);                      // [512][1024]  1 MB
    __bf16* WoT  = (__bf16*)(ws + (1 << 20));          // [1024][512]  1 MB
    __bf16* Qb   = (__bf16*)(ws + (2 << 20));          // [8192][512]  8 MB
    __bf16* Ab   = (__bf16*)(ws + (10 << 20));         // [8192][512]  8 MB
    __bf16* Adrb = (__bf16*)(ws + (18 << 20));         // [128][64]    16 KB

    prep_all<<<1028, 256, 0, stream>>>(Wq, Wo, addresses, WqT, WoT, Adrb);

    // Q = relu(query @ Wq + bq) -> bf16 [8192][512]  (2-deep reg pipeline)
    gemm_qproj<<<dim3(512 / 64, 8192 / 128), 512, 0, stream>>>(
        query, WqT, bq, Qb, 8192, 512, 1024);

    // fused per-token linear memory read (MFMA) -> attn bf16 [8192][512]
    memory_attn_mfma<<<dim3(8192 / 4), 256, 0, stream>>>(Qb, memories, Adrb, Ab);

    // out = attn @ Wo + bo -> f32 [8192][1024]  (3-buffer counted vmcnt)
    gemm_oproj<<<dim3(1024 / 128, 8192 / 128), 512, 0, stream>>>(
        Ab, WoT, bo, out, 8192, 1024, 512);
}

// Round 14
// 112.251 us; speedup vs baseline: 2.0921x; 2.0921x over previous
//
#include <hip/hip_runtime.h>

typedef __bf16 bf16x8 __attribute__((ext_vector_type(8)));
typedef __bf16 bf16x4 __attribute__((ext_vector_type(4)));
typedef __bf16 bf16x2 __attribute__((ext_vector_type(2)));
typedef float  f32x4  __attribute__((ext_vector_type(4)));

// CK-pattern async global->LDS (16B per lane, wave-uniform LDS base).
__device__ __forceinline__ void gload_lds16(const void* g, void* l) {
    auto gp = reinterpret_cast<const __attribute__((address_space(1))) unsigned int*>(
        reinterpret_cast<uintptr_t>(g));
    auto lp = reinterpret_cast<__attribute__((address_space(3))) unsigned int*>(
        reinterpret_cast<uintptr_t>(l));
    __builtin_amdgcn_global_load_lds(gp, lp, 16, 0, 0);
}

// Raw barriers with counted waits (T4/m201 discipline).
__device__ __forceinline__ void barrier_lgkm() {
    __builtin_amdgcn_sched_barrier(0);
    asm volatile("s_waitcnt lgkmcnt(0)" ::: "memory");
    __builtin_amdgcn_s_barrier();
    __builtin_amdgcn_sched_barrier(0);
}
__device__ __forceinline__ void barrier_vm2_lgkm() {
    __builtin_amdgcn_sched_barrier(0);
    asm volatile("s_waitcnt vmcnt(2) lgkmcnt(0)" ::: "memory");
    __builtin_amdgcn_s_barrier();
    __builtin_amdgcn_sched_barrier(0);
}
__device__ __forceinline__ void barrier_vm0_lgkm() {
    __builtin_amdgcn_sched_barrier(0);
    asm volatile("s_waitcnt vmcnt(0) lgkmcnt(0)" ::: "memory");
    __builtin_amdgcn_s_barrier();
    __builtin_amdgcn_sched_barrier(0);
}

// XCD-aware swizzle for 512-block GEMM grids (8 n-blocks x 64 m-rows).
__device__ __forceinline__ void xcd_remap(int lin, int& bx, int& by) {
    const int wgid = (lin & 7) * 64 + (lin >> 3);
    bx = wgid & 7;
    by = wgid >> 3;
}

// ---------------------------------------------------------------------------
// Merged prep (1 launch): Wq/Wo transposes + addresses->bf16.  (unchanged)
// ---------------------------------------------------------------------------
__global__ __launch_bounds__(256) void prep_all(
    const float* __restrict__ Wq, const float* __restrict__ Wo,
    const float* __restrict__ adr,
    __bf16* __restrict__ WqT, __bf16* __restrict__ WoT,
    __bf16* __restrict__ adrb)
{
    __shared__ float tile[32][33];
    const int bid = blockIdx.x, tid = threadIdx.x;

    if (bid < 1024) {
        const float* src; __bf16* dst; int R, C, r0, c0;
        if (bid < 512) {             // Wq [1024][512] -> WqT [512][1024]
            src = Wq; dst = WqT; R = 1024; C = 512;
            c0 = (bid & 15) * 32; r0 = (bid >> 4) * 32;
        } else {                     // Wo [512][1024] -> WoT [1024][512]
            const int b = bid - 512;
            src = Wo; dst = WoT; R = 512; C = 1024;
            c0 = (b & 31) * 32; r0 = (b >> 5) * 32;
        }
        const int tx = tid & 31, ty = tid >> 5;
        #pragma unroll
        for (int i = ty; i < 32; i += 8)
            tile[i][tx] = src[(size_t)(r0 + i) * C + c0 + tx];
        __syncthreads();
        #pragma unroll
        for (int i = ty; i < 32; i += 8)
            dst[(size_t)(c0 + i) * R + r0 + tx] = (__bf16)tile[tx][i];
    } else {                         // addresses [128][64] f32 -> bf16
        const int i = (bid - 1024) * 256 + tid;
        f32x4 a = ((const f32x4*)adr)[2 * i];
        f32x4 b = ((const f32x4*)adr)[2 * i + 1];
        bf16x8 o;
        #pragma unroll
        for (int j = 0; j < 4; ++j) { o[j] = (__bf16)a[j]; o[4 + j] = (__bf16)b[j]; }
        ((bf16x8*)adrb)[i] = o;
    }
}

// ---------------------------------------------------------------------------
// Q-proj GEMM, 512 threads (8 waves, 4m x 2n; wave tile 32x32).
// 2-step-deep register pipeline with NAMED sets X/Y (rule #20: no runtime-
// indexed register arrays) + explicit 2-step loop body.  Raw lgkm-only
// barriers: reg-load waits land at the data-dependent ds_writes (one full
// step of covered latency), never drained at the barrier.
//   even step t:  compute LDS[0](t);  load t+2 -> X;  write Y(t+1) -> LDS[1]
//   odd  step t+1: compute LDS[1](t+1); load t+3 -> Y; write X(t+2) -> LDS[0]
// ---------------------------------------------------------------------------
__global__ __launch_bounds__(512) void gemm_qproj(
    const float* __restrict__ A, const __bf16* __restrict__ BT,
    const float* __restrict__ bias, __bf16* __restrict__ Out,
    int M, int N, int K)
{
    __shared__ __bf16 As[2][128][40];
    __shared__ __bf16 Bs[2][64][32];

    const int tid = threadIdx.x, lane = tid & 63, w = tid >> 6;
    const int wm = w >> 1, wn = w & 1;          // 4 x 2 wave grid
    int bx, by;
    xcd_remap(blockIdx.x + 8 * blockIdx.y, bx, by);
    const int m0 = by * 128, n0 = bx * 64;
    const int r = lane & 15, g = lane >> 4;

    const int arow = tid >> 2, ac8 = (tid & 3) * 8;     // A: 8 f32/thread/tile
    const float* gA = A + (size_t)(m0 + arow) * K + ac8;
    const bool bstage = (w < 4);                        // B: waves 0-3 only
    const int brow = 16 * (w & 3) + (lane >> 2), bc8 = (lane & 3) * 8;
    const __bf16* gB = BT + (size_t)(n0 + brow) * K + bc8;

    f32x4 acc[2][2];
    const f32x4 zero = {0.f, 0.f, 0.f, 0.f};
    #pragma unroll
    for (int mi = 0; mi < 2; ++mi)
        #pragma unroll
        for (int ni = 0; ni < 2; ++ni) acc[mi][ni] = zero;

    const int NT = K / 32;                              // 32 (even, >= 4)

    // ---- named pipeline register sets (NO arrays) ----
    f32x4 xa0, xa1, ya0, ya1;
    bf16x8 xb, yb;

    // ---- prologue: tile0 -> X, tile1 -> Y; write X(tile0) -> LDS[0] ----
    xa0 = *(const f32x4*)(gA);      xa1 = *(const f32x4*)(gA + 4);
    ya0 = *(const f32x4*)(gA + 32); ya1 = *(const f32x4*)(gA + 36);
    if (bstage) { xb = *(const bf16x8*)(gB); yb = *(const bf16x8*)(gB + 32); }
    {
        bf16x8 bl;
        #pragma unroll
        for (int j = 0; j < 4; ++j) { bl[j] = (__bf16)xa0[j]; bl[4 + j] = (__bf16)xa1[j]; }
        *(bf16x8*)&As[0][arow][ac8] = bl;
        if (bstage) *(bf16x8*)&Bs[0][brow][bc8] = xb;
    }
    barrier_lgkm();

    for (int tt = 0; tt < NT - 2; tt += 2) {
        // ===== even step t = tt: compute LDS[0] =====
        xa0 = *(const f32x4*)(gA + (tt + 2) * 32);
        xa1 = *(const f32x4*)(gA + (tt + 2) * 32 + 4);
        if (bstage) xb = *(const bf16x8*)(gB + (tt + 2) * 32);
        {
            bf16x8 af0, af1, bf0, bf1;
            af0 = *(const bf16x8*)&As[0][wm * 32 + r][g * 8];
            af1 = *(const bf16x8*)&As[0][wm * 32 + 16 + r][g * 8];
            bf0 = *(const bf16x8*)&Bs[0][wn * 32 + r][g * 8];
            bf1 = *(const bf16x8*)&Bs[0][wn * 32 + 16 + r][g * 8];
            acc[0][0] = __builtin_amdgcn_mfma_f32_16x16x32_bf16(af0, bf0, acc[0][0], 0, 0, 0);
            acc[0][1] = __builtin_amdgcn_mfma_f32_16x16x32_bf16(af0, bf1, acc[0][1], 0, 0, 0);
            acc[1][0] = __builtin_amdgcn_mfma_f32_16x16x32_bf16(af1, bf0, acc[1][0], 0, 0, 0);
            acc[1][1] = __builtin_amdgcn_mfma_f32_16x16x32_bf16(af1, bf1, acc[1][1], 0, 0, 0);
        }
        {   // write Y (tile tt+1) -> LDS[1]
            bf16x8 bl;
            #pragma unroll
            for (int j = 0; j < 4; ++j) { bl[j] = (__bf16)ya0[j]; bl[4 + j] = (__bf16)ya1[j]; }
            *(bf16x8*)&As[1][arow][ac8] = bl;
            if (bstage) *(bf16x8*)&Bs[1][brow][bc8] = yb;
        }
        barrier_lgkm();

        // ===== odd step t = tt+1: compute LDS[1] =====
        ya0 = *(const f32x4*)(gA + (tt + 3) * 32);
        ya1 = *(const f32x4*)(gA + (tt + 3) * 32 + 4);
        if (bstage) yb = *(const bf16x8*)(gB + (tt + 3) * 32);
        {
            bf16x8 af0, af1, bf0, bf1;
            af0 = *(const bf16x8*)&As[1][wm * 32 + r][g * 8];
            af1 = *(const bf16x8*)&As[1][wm * 32 + 16 + r][g * 8];
            bf0 = *(const bf16x8*)&Bs[1][wn * 32 + r][g * 8];
            bf1 = *(const bf16x8*)&Bs[1][wn * 32 + 16 + r][g * 8];
            acc[0][0] = __builtin_amdgcn_mfma_f32_16x16x32_bf16(af0, bf0, acc[0][0], 0, 0, 0);
            acc[0][1] = __builtin_amdgcn_mfma_f32_16x16x32_bf16(af0, bf1, acc[0][1], 0, 0, 0);
            acc[1][0] = __builtin_amdgcn_mfma_f32_16x16x32_bf16(af1, bf0, acc[1][0], 0, 0, 0);
            acc[1][1] = __builtin_amdgcn_mfma_f32_16x16x32_bf16(af1, bf1, acc[1][1], 0, 0, 0);
        }
        {   // write X (tile tt+2) -> LDS[0]
            bf16x8 bl;
            #pragma unroll
            for (int j = 0; j < 4; ++j) { bl[j] = (__bf16)xa0[j]; bl[4 + j] = (__bf16)xa1[j]; }
            *(bf16x8*)&As[0][arow][ac8] = bl;
            if (bstage) *(bf16x8*)&Bs[0][brow][bc8] = xb;
        }
        barrier_lgkm();
    }

    // ===== tail: t = NT-2 (LDS[0]) then t = NT-1 (LDS[1]) =====
    {
        bf16x8 af0, af1, bf0, bf1;
        af0 = *(const bf16x8*)&As[0][wm * 32 + r][g * 8];
        af1 = *(const bf16x8*)&As[0][wm * 32 + 16 + r][g * 8];
        bf0 = *(const bf16x8*)&Bs[0][wn * 32 + r][g * 8];
        bf1 = *(const bf16x8*)&Bs[0][wn * 32 + 16 + r][g * 8];
        acc[0][0] = __builtin_amdgcn_mfma_f32_16x16x32_bf16(af0, bf0, acc[0][0], 0, 0, 0);
        acc[0][1] = __builtin_amdgcn_mfma_f32_16x16x32_bf16(af0, bf1, acc[0][1], 0, 0, 0);
        acc[1][0] = __builtin_amdgcn_mfma_f32_16x16x32_bf16(af1, bf0, acc[1][0], 0, 0, 0);
        acc[1][1] = __builtin_amdgcn_mfma_f32_16x16x32_bf16(af1, bf1, acc[1][1], 0, 0, 0);
    }
    {
        bf16x8 bl;
        #pragma unroll
        for (int j = 0; j < 4; ++j) { bl[j] = (__bf16)ya0[j]; bl[4 + j] = (__bf16)ya1[j]; }
        *(bf16x8*)&As[1][arow][ac8] = bl;
        if (bstage) *(bf16x8*)&Bs[1][brow][bc8] = yb;
    }
    barrier_lgkm();
    {
        bf16x8 af0, af1, bf0, bf1;
        af0 = *(const bf16x8*)&As[1][wm * 32 + r][g * 8];
        af1 = *(const bf16x8*)&As[1][wm * 32 + 16 + r][g * 8];
        bf0 = *(const bf16x8*)&Bs[1][wn * 32 + r][g * 8];
        bf1 = *(const bf16x8*)&Bs[1][wn * 32 + 16 + r][g * 8];
        acc[0][0] = __builtin_amdgcn_mfma_f32_16x16x32_bf16(af0, bf0, acc[0][0], 0, 0, 0);
        acc[0][1] = __builtin_amdgcn_mfma_f32_16x16x32_bf16(af0, bf1, acc[0][1], 0, 0, 0);
        acc[1][0] = __builtin_amdgcn_mfma_f32_16x16x32_bf16(af1, bf0, acc[1][0], 0, 0, 0);
        acc[1][1] = __builtin_amdgcn_mfma_f32_16x16x32_bf16(af1, bf1, acc[1][1], 0, 0, 0);
    }

    const int orow = m0 + wm * 32 + g * 4;
    const int ocol = n0 + wn * 32 + r;
    #pragma unroll
    for (int ni = 0; ni < 2; ++ni) {
        const float bb = bias[ocol + ni * 16];
        #pragma unroll
        for (int mi = 0; mi < 2; ++mi) {
            #pragma unroll
            for (int q = 0; q < 4; ++q) {
                float v = fmaxf(acc[mi][ni][q] + bb, 0.f);
                Out[(size_t)(orow + mi * 16 + q) * N + ocol + ni * 16] = (__bf16)v;
            }
        }
    }
}

// ---------------------------------------------------------------------------
// Out-proj GEMM (r13 3-buffer counted-vmcnt — kept; ledger suggests ~9-10 µs).
// ---------------------------------------------------------------------------
__global__ __launch_bounds__(512) void gemm_oproj(
    const __bf16* __restrict__ A, const __bf16* __restrict__ BT,
    const float* __restrict__ bias, float* __restrict__ Out,
    int M, int N, int K)
{
    __shared__ __bf16 As[3][128][32];
    __shared__ __bf16 Bs[3][128][32];

    const int tid = threadIdx.x, lane = tid & 63, w = tid >> 6;
    const int wm = w >> 1, wn = w & 1;          // 4 x 2 wave grid
    int bx, by;
    xcd_remap(blockIdx.x + 8 * blockIdx.y, bx, by);
    const int m0 = by * 128, n0 = bx * 128;
    const int r = lane & 15, g = lane >> 4;

    const int srow = lane >> 2;
    const int scol = (lane & 3) * 8;
    const __bf16* gA = A  + (size_t)(m0 + 16 * w + srow) * K + scol;
    const __bf16* gB = BT + (size_t)(n0 + 16 * w + srow) * K + scol;

    f32x4 acc[2][4];
    const f32x4 zero = {0.f, 0.f, 0.f, 0.f};
    #pragma unroll
    for (int mi = 0; mi < 2; ++mi)
        #pragma unroll
        for (int ni = 0; ni < 4; ++ni) acc[mi][ni] = zero;

    const int NT = K / 32;                              // 16

    gload_lds16(gA,      &As[0][16 * w][0]);
    gload_lds16(gB,      &Bs[0][16 * w][0]);
    gload_lds16(gA + 32, &As[1][16 * w][0]);
    gload_lds16(gB + 32, &Bs[1][16 * w][0]);
    __builtin_amdgcn_sched_barrier(0);
    asm volatile("s_waitcnt vmcnt(2)" ::: "memory");
    __builtin_amdgcn_s_barrier();
    __builtin_amdgcn_sched_barrier(0);

    int buf = 0;
    for (int t = 0; t < NT; ++t) {
        if (t + 2 < NT) {
            const int nb = (buf + 2 >= 3) ? buf - 1 : buf + 2;
            gload_lds16(gA + (t + 2) * 32, &As[nb][16 * w][0]);
            gload_lds16(gB + (t + 2) * 32, &Bs[nb][16 * w][0]);
        }
        bf16x8 af[2], bfr[4];
        #pragma unroll
        for (int mi = 0; mi < 2; ++mi)
            af[mi] = *(const bf16x8*)&As[buf][wm * 32 + mi * 16 + r][g * 8];
        #pragma unroll
        for (int ni = 0; ni < 4; ++ni)
            bfr[ni] = *(const bf16x8*)&Bs[buf][wn * 64 + ni * 16 + r][g * 8];
        #pragma unroll
        for (int mi = 0; mi < 2; ++mi)
            #pragma unroll
            for (int ni = 0; ni < 4; ++ni)
                acc[mi][ni] = __builtin_amdgcn_mfma_f32_16x16x32_bf16(
                    af[mi], bfr[ni], acc[mi][ni], 0, 0, 0);
        if (t + 1 < NT) {
            if (t + 2 < NT) barrier_vm2_lgkm();
            else            barrier_vm0_lgkm();
        }
        buf = (buf + 1 >= 3) ? 0 : buf + 1;
    }

    const int orow = m0 + wm * 32 + g * 4;
    const int ocol = n0 + wn * 64 + r;
    #pragma unroll
    for (int ni = 0; ni < 4; ++ni) {
        const float bb = bias[ocol + ni * 16];
        #pragma unroll
        for (int mi = 0; mi < 2; ++mi) {
            #pragma unroll
            for (int q = 0; q < 4; ++q) {
                Out[(size_t)(orow + mi * 16 + q) * N + ocol + ni * 16]
                    = acc[mi][ni][q] + bb;
            }
        }
    }
}

// ---------------------------------------------------------------------------
// Fused memory attention (MFMA) — at HBM floor (43.7 µs, r8).  Do not touch.
// ---------------------------------------------------------------------------
__device__ __forceinline__ int kbyte(int m, int e) {
    return m * 128 + ((((e >> 3) ^ (m & 7))) << 4) + (e & 7) * 2;
}

__global__ void memory_attn_mfma(
    const __bf16* __restrict__ Q,      // [N][512] bf16 (relu'd q proj)
    const float*  __restrict__ mem,    // [N][128][64] f32
    const __bf16* __restrict__ adrb,   // [128][64] bf16
    __bf16* __restrict__ attn)         // [N][512] bf16
{
    __shared__ __align__(16) unsigned char kbuf[4][4096];
    __shared__ __align__(16) unsigned char tbuf[4][5120];
    __shared__ float denl[4][8];

    const int tid = threadIdx.x, lane = tid & 63, w = tid >> 6;
    const int n = blockIdx.x * 4 + w;
    const int v = lane & 15, g = lane >> 4;

    unsigned char* kb = kbuf[w];
    unsigned char* tb = tbuf[w];

    const __bf16* qp = Q + (size_t)n * 512 + v * 64 + 8 * g;
    const bf16x8 qf0 = *(const bf16x8*)(qp);
    const bf16x8 qf1 = *(const bf16x8*)(qp + 32);

    f32x4 acc[4];
    const f32x4 zero = {0.f, 0.f, 0.f, 0.f};
    #pragma unroll
    for (int nb = 0; nb < 4; ++nb) acc[nb] = zero;
    float psum = 0.f;

    for (int c = 0; c < 4; ++c) {
        const int mb = c * 32;
        #pragma unroll
        for (int i = 0; i < 4; ++i) {
            const int mo = 8 * i + 2 * g;
            const int e  = 4 * v;
            const float* pm = mem + (((size_t)n * 128 + mb + mo) * 64 + e);
            const f32x4 m0 = *(const f32x4*)pm;
            const f32x4 m1 = *(const f32x4*)(pm + 64);
            const bf16x4 a0 = *(const bf16x4*)(adrb + (size_t)(mb + mo) * 64 + e);
            const bf16x4 a1 = *(const bf16x4*)(adrb + (size_t)(mb + mo + 1) * 64 + e);
            bf16x4 k0, k1;
            #pragma unroll
            for (int j = 0; j < 4; ++j) {
                k0[j] = (__bf16)fmaxf(m0[j] + (float)a0[j], 0.f);
                k1[j] = (__bf16)fmaxf(m1[j] + (float)a1[j], 0.f);
            }
            *(bf16x4*)(kb + kbyte(mo,     e)) = k0;
            *(bf16x4*)(kb + kbyte(mo + 1, e)) = k1;
            const int kap = 8 * ((mo >> 2) & 3) + 4 * (mo >> 4) + (mo & 3);
            #pragma unroll
            for (int j2 = 0; j2 < 4; ++j2) {
                bf16x2 p = { (__bf16)m0[j2], (__bf16)m1[j2] };
                *(bf16x2*)(tb + (size_t)(e + j2) * 80 + kap * 2) = p;
            }
        }

        f32x4 sA0 = zero, sA1 = zero;
        {
            const bf16x8 a00 = *(const bf16x8*)(kb + kbyte(v,      8 * g));
            const bf16x8 a01 = *(const bf16x8*)(kb + kbyte(v,      32 + 8 * g));
            const bf16x8 a10 = *(const bf16x8*)(kb + kbyte(v + 16, 8 * g));
            const bf16x8 a11 = *(const bf16x8*)(kb + kbyte(v + 16, 32 + 8 * g));
            sA0 = __builtin_amdgcn_mfma_f32_16x16x32_bf16(a00, qf0, sA0, 0, 0, 0);
            sA0 = __builtin_amdgcn_mfma_f32_16x16x32_bf16(a01, qf1, sA0, 0, 0, 0);
            sA1 = __builtin_amdgcn_mfma_f32_16x16x32_bf16(a10, qf0, sA1, 0, 0, 0);
            sA1 = __builtin_amdgcn_mfma_f32_16x16x32_bf16(a11, qf1, sA1, 0, 0, 0);
        }
        psum += sA0[0] + sA0[1] + sA0[2] + sA0[3]
              + sA1[0] + sA1[1] + sA1[2] + sA1[3];

        bf16x8 pa;
        #pragma unroll
        for (int q = 0; q < 4; ++q) {
            pa[q]     = (__bf16)sA0[q];
            pa[4 + q] = (__bf16)sA1[q];
        }

        #pragma unroll
        for (int nb = 0; nb < 4; ++nb) {
            const bf16x8 bf = *(const bf16x8*)(tb + (size_t)(16 * nb + v) * 80 + 16 * g);
            acc[nb] = __builtin_amdgcn_mfma_f32_16x16x32_bf16(pa, bf, acc[nb], 0, 0, 0);
        }
    }

    psum += __shfl_xor(psum, 16);
    psum += __shfl_xor(psum, 32);
    if (lane < 8) denl[w][lane] = psum;

    if (g < 2) {
        const f32x4 d4 = *(const f32x4*)&denl[w][4 * g];
        float inv[4];
        #pragma unroll
        for (int q = 0; q < 4; ++q) inv[q] = 1.f / (d4[q] + 1e-5f);
        #pragma unroll
        for (int nb = 0; nb < 4; ++nb) {
            #pragma unroll
            for (int q = 0; q < 4; ++q) {
                attn[(size_t)n * 512 + (4 * g + q) * 64 + 16 * nb + v] =
                    (__bf16)(acc[nb][q] * inv[q]);
            }
        }
    }
}

// ---------------------------------------------------------------------------
extern "C" void kernel_launch(void* const* d_in, const int* in_sizes, int n_in,
                              void* d_out, int out_size, void* d_ws, size_t ws_size,
                              hipStream_t stream)
{
    const float* query     = (const float*)d_in[0];
    const float* addresses = (const float*)d_in[1];
    const float* memories  = (const float*)d_in[2];
    const float* Wq        = (const float*)d_in[3];
    const float* bq        = (const float*)d_in[4];
    const float* Wo        = (const float*)d_in[5];
    const float* bo        = (const float*)d_in[6];
    float* out = (float*)d_out;

    char* ws = (char*)d_ws;
    __bf16* WqT  = (__bf16*)(ws);                      // [512][1024]  1 MB
    __bf16* WoT  = (__bf16*)(ws + (1 << 20));          // [1024][512]  1 MB
    __bf16* Qb   = (__bf16*)(ws + (2 << 20));          // [8192][512]  8 MB
    __bf16* Ab   = (__bf16*)(ws + (10 << 20));         // [8192][512]  8 MB
    __bf16* Adrb = (__bf16*)(ws + (18 << 20));         // [128][64]    16 KB

    prep_all<<<1028, 256, 0, stream>>>(Wq, Wo, addresses, WqT, WoT, Adrb);

    // Q = relu(query @ Wq + bq) -> bf16 [8192][512]  (named-reg 2-deep pipe)
    gemm_qproj<<<dim3(512 / 64, 8192 / 128), 512, 0, stream>>>(
        query, WqT, bq, Qb, 8192, 512, 1024);

    // fused per-token linear memory read (MFMA) -> attn bf16 [8192][512]
    memory_attn_mfma<<<dim3(8192 / 4), 256, 0, stream>>>(Qb, memories, Adrb, Ab);

    // out = attn @ Wo + bo -> f32 [8192][1024]  (3-buffer counted vmcnt)
    gemm_oproj<<<dim3(1024 / 128, 8192 / 128), 512, 0, stream>>>(
        Ab, WoT, bo, out, 8192, 1024, 512);
}